// Round 4
// baseline (141.180 us; speedup 1.0000x reference)
//
#include <hip/hip_runtime.h>
#include <hip/hip_bf16.h>
#include <math.h>

// Problem constants (b,c,w,h,z) = (2,64,64,64,64), nz = 32
#define THRESH_SP 1.5f
#define WHZc   262144      // 64*64*64
#define CWHZc  16777216    // 64*WHZc

// workspace layout
// floats:  [0..128)  p sums [2][64];  [128..8320) slot stats [32][2][128]
#define WS_PSUM   0
#define WS_SLOT   128
#define WS_ZERO_N 8320
// bytes:
#define WS_W16_BYTE  65536                    // gw16/pw16/Ww16, 3*4096 u16 = 24 KB
#define WS_WY_BYTE   131072                   // wy bf16 [2][CWHZ]
#define WS_X16_BYTE  (WS_WY_BYTE + 2u*CWHZc*2u)        // x bf16 [2][CWHZ]
#define WS_W16_NEED  (WS_W16_BYTE + 3u*4096u*2u)
#define WS_WY_NEED   (WS_WY_BYTE + 2u*CWHZc*2u)
#define WS_X16_NEED  (WS_X16_BYTE + 2u*CWHZc*2u)       // ~134.3 MB

typedef __attribute__((ext_vector_type(8))) short bf16x8;
typedef __attribute__((ext_vector_type(4))) float floatx4;

#define MFMA(a, b, c) __builtin_amdgcn_mfma_f32_16x16x32_bf16((a), (b), (c), 0, 0, 0)

__device__ __forceinline__ unsigned short f2b(float f) {
    __hip_bfloat16 h = __float2bfloat16(f);      // native RNE cvt
    return __builtin_bit_cast(unsigned short, h);
}
__device__ __forceinline__ float b2f(unsigned short h) {
    unsigned int u = ((unsigned int)h) << 16;
    return __builtin_bit_cast(float, u);
}
__device__ __forceinline__ bf16x8 ldfrag(const unsigned short* p, int elem_off) {
    return *(const bf16x8*)(p + elem_off);
}

// zero stats + convert the three 64x64 weight matrices to bf16 (once)
__global__ __launch_bounds__(256) void k_prep(const float* __restrict__ gw,
                                              const float* __restrict__ pw,
                                              const float* __restrict__ Ww,
                                              float* __restrict__ ws,
                                              unsigned short* __restrict__ w16,
                                              int usew16) {
    const int i = blockIdx.x * 256 + threadIdx.x;
    if (i < WS_ZERO_N) ws[i] = 0.0f;
    if (usew16 && i < 4096) {
        w16[i]        = f2b(gw[i]);
        w16[4096 + i] = f2b(pw[i]);
        w16[8192 + i] = f2b(Ww[i]);
    }
}

// p[b][z] partial sums + bf16 copy of x
__global__ __launch_bounds__(256) void k_pmean(const float* __restrict__ x,
                                               const float* __restrict__ sp,
                                               float* __restrict__ ws,
                                               unsigned short* __restrict__ x16,
                                               int usex16) {
    const int b = blockIdx.x >> 9;
    if (sp[b*3 + 2] > THRESH_SP) return;
    const int jb = blockIdx.x & 511;
    __shared__ float s[64];
    const int t = threadIdx.x;
    if (t < 64) s[t] = 0.0f;
    __syncthreads();
    const int idx4 = jb * 256 + t;
    const int z0 = (idx4 & 15) * 4;
    float a0 = 0.f, a1 = 0.f, a2 = 0.f, a3 = 0.f;
    const float* xb = x + (size_t)b * CWHZc;
    unsigned short* xo = x16 + (size_t)b * CWHZc;
#pragma unroll 4
    for (int it = 0; it < 32; ++it) {
        const size_t e4 = (size_t)(idx4 + it * 131072);
        const float4 v = *(const float4*)&xb[e4 * 4];
        a0 += v.x; a1 += v.y; a2 += v.z; a3 += v.w;
        if (usex16) {
            uint2 pk;
            pk.x = (unsigned int)f2b(v.x) | ((unsigned int)f2b(v.y) << 16);
            pk.y = (unsigned int)f2b(v.z) | ((unsigned int)f2b(v.w) << 16);
            *(uint2*)&xo[e4 * 4] = pk;
        }
    }
    a0 += __shfl_xor(a0, 16); a0 += __shfl_xor(a0, 32);
    a1 += __shfl_xor(a1, 16); a1 += __shfl_xor(a1, 32);
    a2 += __shfl_xor(a2, 16); a2 += __shfl_xor(a2, 32);
    a3 += __shfl_xor(a3, 16); a3 += __shfl_xor(a3, 32);
    if ((t & 63) < 16) {
        unsafeAtomicAdd(&s[z0 + 0], a0);
        unsafeAtomicAdd(&s[z0 + 1], a1);
        unsafeAtomicAdd(&s[z0 + 2], a2);
        unsafeAtomicAdd(&s[z0 + 3], a3);
    }
    __syncthreads();
    if (t < 64) unsafeAtomicAdd(&ws[WS_PSUM + b * 64 + t], s[t]);
}

// One block per (b, wi, hi). p factored out of xp (scales MFMA output rows).
// A-fragments of bf16 x^T loaded once, reused across G / PHI / F.
__global__ __launch_bounds__(256, 4) void k_main(
    const float* __restrict__ x, const float* __restrict__ sp,
    const float* __restrict__ gw, const float* __restrict__ gb,
    const float* __restrict__ pw, const float* __restrict__ pb,
    const float* __restrict__ Wwp, const float* __restrict__ Wbp,
    float* __restrict__ out, unsigned short* __restrict__ wy16, int use16,
    const unsigned short* __restrict__ w16, int usew16,
    const unsigned short* __restrict__ x16, int usex16,
    float* __restrict__ ws) {
    const int blk = blockIdx.x;
    const int b = blk >> 12;
    if (sp[b*3 + 2] > THRESH_SP) return;
    const int wh = blk & 4095;
    const int xbase = b * CWHZc + wh * 64;

    __shared__ unsigned short xT[64 * 72];   // x^T[z][c] bf16; later y^T[z][i]
    __shared__ unsigned short wb[64 * 72];   // gw -> pw -> Ww  [row][k] bf16
    __shared__ unsigned short gpT[64 * 40];  // pooled g [i][n]
    __shared__ unsigned short phpN[32 * 72]; // pooled phi^T [n][i]; aliased f32 stats[128]
    __shared__ unsigned short aT[64 * 40];   // softmax a [z][n]
    __shared__ float p_s[64];

    const int t  = threadIdx.x;
    const int l  = t & 63;
    const int lr = l & 15;
    const int lq = l >> 4;
    const int zt = (t >> 6) << 4;

    // ---- stage x^T (bf16 transposed) ----
    if (usex16) {
        const unsigned short* xs = x16 + xbase;
#pragma unroll
        for (int k = 0; k < 2; ++k) {
            const int f = t + (k << 8);
            const int c = f >> 3, seg = f & 7;
            uint4 q = *(const uint4*)&xs[c * WHZc + seg * 8];
            const unsigned short* qs = (const unsigned short*)&q;
#pragma unroll
            for (int j = 0; j < 8; ++j) xT[(seg*8 + j)*72 + c] = qs[j];
        }
    } else {
#pragma unroll
        for (int k = 0; k < 4; ++k) {
            const int f = t + (k << 8);
            const int c = f & 63, zq = f >> 6;
            const float4 v = *(const float4*)&x[xbase + c * WHZc + zq * 4];
            xT[(zq*4 + 0)*72 + c] = f2b(v.x);
            xT[(zq*4 + 1)*72 + c] = f2b(v.y);
            xT[(zq*4 + 2)*72 + c] = f2b(v.z);
            xT[(zq*4 + 3)*72 + c] = f2b(v.w);
        }
    }
    // ---- stage gw ----
    if (usew16) {
#pragma unroll
        for (int k = 0; k < 2; ++k) {
            const int f = t + (k << 8);
            const int i = f >> 3, seg = f & 7;
            *(uint4*)&wb[i*72 + seg*8] = *(const uint4*)&w16[i*64 + seg*8];
        }
    } else {
#pragma unroll
        for (int k = 0; k < 4; ++k) {
            const int f = t + (k << 8);
            const int i = f >> 4, c4 = f & 15;
            const float4 v = *(const float4*)&gw[i*64 + c4*4];
            uint2 pk;
            pk.x = (unsigned int)f2b(v.x) | ((unsigned int)f2b(v.y) << 16);
            pk.y = (unsigned int)f2b(v.z) | ((unsigned int)f2b(v.w) << 16);
            *(uint2*)&wb[i*72 + c4*4] = pk;
        }
    }
    if (t < 64) p_s[t] = ws[WS_PSUM + b*64 + t] * (1.0f / 262144.0f);
    __syncthreads();

    // persistent A-fragments of x^T (rows z = zt+lr, k = c)
    const bf16x8 a0 = ldfrag(xT, (zt + lr)*72 + lq*8);
    const bf16x8 a1 = ldfrag(xT, (zt + lr)*72 + lq*8 + 32);
    const float pz0 = p_s[zt + lq*4 + 0], pz1 = p_s[zt + lq*4 + 1];
    const float pz2 = p_s[zt + lq*4 + 2], pz3 = p_s[zt + lq*4 + 3];

    // ---- G: D[z][i] = sum_c x[z][c]*gw[i][c] + gb; maxpool z-pairs -> gpT[i][n] ----
    {
        const int n0 = (zt >> 1) + lq*2;
#pragma unroll
        for (int ti = 0; ti < 4; ++ti) {
            const int i = ti*16 + lr;
            const float bv = gb[i];
            floatx4 acc = {bv, bv, bv, bv};
            acc = MFMA(a0, ldfrag(wb, i*72 + lq*8), acc);
            acc = MFMA(a1, ldfrag(wb, i*72 + lq*8 + 32), acc);
            unsigned int pk = (unsigned int)f2b(fmaxf(acc[0], acc[1])) |
                              ((unsigned int)f2b(fmaxf(acc[2], acc[3])) << 16);
            *(unsigned int*)&gpT[i*40 + n0] = pk;
        }
    }
    __syncthreads();

    // ---- restage pw ----
    if (usew16) {
#pragma unroll
        for (int k = 0; k < 2; ++k) {
            const int f = t + (k << 8);
            const int i = f >> 3, seg = f & 7;
            *(uint4*)&wb[i*72 + seg*8] = *(const uint4*)&w16[4096 + i*64 + seg*8];
        }
    } else {
#pragma unroll
        for (int k = 0; k < 4; ++k) {
            const int f = t + (k << 8);
            const int i = f >> 4, c4 = f & 15;
            const float4 v = *(const float4*)&pw[i*64 + c4*4];
            uint2 pk;
            pk.x = (unsigned int)f2b(v.x) | ((unsigned int)f2b(v.y) << 16);
            pk.y = (unsigned int)f2b(v.z) | ((unsigned int)f2b(v.w) << 16);
            *(uint2*)&wb[i*72 + c4*4] = pk;
        }
    }
    __syncthreads();

    // ---- PHI: phi[z][i] = p[z]*(X Wp^T)[z][i] + pb; pool -> phpN[n][i] ----
    {
        const int n0 = (zt >> 1) + lq*2;
#pragma unroll
        for (int ti = 0; ti < 4; ++ti) {
            const int i = ti*16 + lr;
            floatx4 acc = {0.f, 0.f, 0.f, 0.f};
            acc = MFMA(a0, ldfrag(wb, i*72 + lq*8), acc);
            acc = MFMA(a1, ldfrag(wb, i*72 + lq*8 + 32), acc);
            const float bv = pb[i];
            const float v0 = fmaf(acc[0], pz0, bv), v1 = fmaf(acc[1], pz1, bv);
            const float v2 = fmaf(acc[2], pz2, bv), v3 = fmaf(acc[3], pz3, bv);
            phpN[n0*72 + i]       = f2b(fmaxf(v0, v1));
            phpN[(n0 + 1)*72 + i] = f2b(fmaxf(v2, v3));
        }
    }
    __syncthreads();

    // ---- F + softmax; a -> aT; then stage Ww ----
    {
        floatx4 f0 = {0.f, 0.f, 0.f, 0.f}, f1 = {0.f, 0.f, 0.f, 0.f};
        f0 = MFMA(a0, ldfrag(phpN, lr*72 + lq*8), f0);
        f0 = MFMA(a1, ldfrag(phpN, lr*72 + lq*8 + 32), f0);
        f1 = MFMA(a0, ldfrag(phpN, (16 + lr)*72 + lq*8), f1);
        f1 = MFMA(a1, ldfrag(phpN, (16 + lr)*72 + lq*8 + 32), f1);
        const float pz[4] = {pz0, pz1, pz2, pz3};
#pragma unroll
        for (int r = 0; r < 4; ++r) {
            const float fr0 = f0[r] * pz[r], fr1 = f1[r] * pz[r];
            float m = fmaxf(fr0, fr1);
            m = fmaxf(m, __shfl_xor(m, 1)); m = fmaxf(m, __shfl_xor(m, 2));
            m = fmaxf(m, __shfl_xor(m, 4)); m = fmaxf(m, __shfl_xor(m, 8));
            const float e0 = __expf(fr0 - m), e1 = __expf(fr1 - m);
            float s = e0 + e1;
            s += __shfl_xor(s, 1); s += __shfl_xor(s, 2);
            s += __shfl_xor(s, 4); s += __shfl_xor(s, 8);
            const float inv = 1.0f / s;
            const int z = zt + lq*4 + r;
            aT[z*40 + lr]      = f2b(e0 * inv);
            aT[z*40 + lr + 16] = f2b(e1 * inv);
        }
        if (usew16) {
#pragma unroll
            for (int k = 0; k < 2; ++k) {
                const int f = t + (k << 8);
                const int i = f >> 3, seg = f & 7;
                *(uint4*)&wb[i*72 + seg*8] = *(const uint4*)&w16[8192 + i*64 + seg*8];
            }
        } else {
#pragma unroll
            for (int k = 0; k < 4; ++k) {
                const int f = t + (k << 8);
                const int i = f >> 4, c4 = f & 15;
                const float4 v = *(const float4*)&Wwp[i*64 + c4*4];
                uint2 pk;
                pk.x = (unsigned int)f2b(v.x) | ((unsigned int)f2b(v.y) << 16);
                pk.y = (unsigned int)f2b(v.z) | ((unsigned int)f2b(v.w) << 16);
                *(uint2*)&wb[i*72 + c4*4] = pk;
            }
        }
    }
    __syncthreads();

    // ---- Y: y[z][i] = sum_n a[z][n]*gp[i][n] -> y^T into xT; zero stats ----
    {
        float* statsf = (float*)phpN;
        if (t < 128) statsf[t] = 0.0f;
        const bf16x8 av = ldfrag(aT, (zt + lr)*40 + lq*8);
#pragma unroll
        for (int ti = 0; ti < 4; ++ti) {
            floatx4 acc = {0.f, 0.f, 0.f, 0.f};
            acc = MFMA(av, ldfrag(gpT, (ti*16 + lr)*40 + lq*8), acc);
#pragma unroll
            for (int r = 0; r < 4; ++r)
                xT[(zt + lq*4 + r)*72 + ti*16 + lr] = f2b(acc[r]);
        }
    }
    __syncthreads();

    // ---- W: wy^T[z][co] = sum_i y[z][i]*Ww[co][i] + Wb; store + BN stats ----
    {
        float* statsf = (float*)phpN;
        const bf16x8 y0 = ldfrag(xT, (zt + lr)*72 + lq*8);
        const bf16x8 y1 = ldfrag(xT, (zt + lr)*72 + lq*8 + 32);
#pragma unroll
        for (int ti = 0; ti < 4; ++ti) {
            const int co = ti*16 + lr;
            const float bv = Wbp[co];
            floatx4 acc = {bv, bv, bv, bv};
            acc = MFMA(y0, ldfrag(wb, co*72 + lq*8), acc);
            acc = MFMA(y1, ldfrag(wb, co*72 + lq*8 + 32), acc);
            if (use16) {
                uint2 pk;
                pk.x = (unsigned int)f2b(acc[0]) | ((unsigned int)f2b(acc[1]) << 16);
                pk.y = (unsigned int)f2b(acc[2]) | ((unsigned int)f2b(acc[3]) << 16);
                *(uint2*)&wy16[(size_t)xbase + co * WHZc + zt + lq*4] = pk;
            } else {
                *(float4*)&out[xbase + co * WHZc + zt + lq*4] = *(float4*)&acc;
            }
            float s1 = acc[0] + acc[1] + acc[2] + acc[3];
            float s2 = acc[0]*acc[0] + acc[1]*acc[1] + acc[2]*acc[2] + acc[3]*acc[3];
            s1 += __shfl_xor(s1, 16); s1 += __shfl_xor(s1, 32);
            s2 += __shfl_xor(s2, 16); s2 += __shfl_xor(s2, 32);
            if (lq == 0) {
                atomicAdd(&statsf[co*2],     s1);
                atomicAdd(&statsf[co*2 + 1], s2);
            }
        }
    }
    __syncthreads();
    {
        const float* statsf = (const float*)phpN;
        if (t < 128) {
            const int slot = blk & 31;
            unsafeAtomicAdd(&ws[WS_SLOT + (slot*2 + b)*128 + t], statsf[t]);
        }
    }
}

// out = gate ? wy*sc + sh + x : x  (BN finalize folded in)
__global__ __launch_bounds__(256) void k_final(const float* __restrict__ x,
                                               const float* __restrict__ sp,
                                               const float* __restrict__ gamma,
                                               const float* __restrict__ beta,
                                               float* __restrict__ out,
                                               const unsigned short* __restrict__ wy16,
                                               int use16,
                                               const unsigned short* __restrict__ x16,
                                               int usex16,
                                               const float* __restrict__ ws) {
    const bool use0 = sp[2] <= THRESH_SP;
    const bool use1 = sp[5] <= THRESH_SP;
    __shared__ float scf[128], shf[128];
    if ((use0 || use1) && threadIdx.x < 128) {
        const int t = threadIdx.x;
        const int b = t >> 6, c = t & 63;
        float S1 = 0.f, S2 = 0.f;
        for (int s = 0; s < 32; s++) {
            S1 += ws[WS_SLOT + (s*2 + b)*128 + c*2 + 0];
            S2 += ws[WS_SLOT + (s*2 + b)*128 + c*2 + 1];
        }
        const float N = 262144.0f;
        const float mu = S1 / N;
        const float var = fmaxf(S2 / N - mu * mu, 0.0f);
        const float sc = gamma[c] * rsqrtf(var + 1e-5f);
        scf[t] = sc;
        shf[t] = beta[c] - mu * sc;
    }
    __syncthreads();
    const int nf4 = (2 * CWHZc) / 4;
    for (int i4 = blockIdx.x * blockDim.x + threadIdx.x; i4 < nf4;
         i4 += gridDim.x * blockDim.x) {
        const int idx = i4 * 4;
        const int b = idx >> 24;
        const bool use = b ? use1 : use0;
        float4 ov;
        if (use) {
            const int c = (idx >> 18) & 63;
            const float scv = scf[b * 64 + c];
            const float shv = shf[b * 64 + c];
            float x0, x1, x2, x3;
            if (usex16) {
                const uint2 q = *(const uint2*)&x16[idx];
                x0 = b2f((unsigned short)(q.x & 0xffffu));
                x1 = b2f((unsigned short)(q.x >> 16));
                x2 = b2f((unsigned short)(q.y & 0xffffu));
                x3 = b2f((unsigned short)(q.y >> 16));
            } else {
                const float4 xv = *(const float4*)&x[idx];
                x0 = xv.x; x1 = xv.y; x2 = xv.z; x3 = xv.w;
            }
            float w0, w1, w2, w3;
            if (use16) {
                const uint2 q = *(const uint2*)&wy16[idx];
                w0 = b2f((unsigned short)(q.x & 0xffffu));
                w1 = b2f((unsigned short)(q.x >> 16));
                w2 = b2f((unsigned short)(q.y & 0xffffu));
                w3 = b2f((unsigned short)(q.y >> 16));
            } else {
                const float4 wy = *(const float4*)&out[idx];
                w0 = wy.x; w1 = wy.y; w2 = wy.z; w3 = wy.w;
            }
            ov.x = w0 * scv + shv + x0;
            ov.y = w1 * scv + shv + x1;
            ov.z = w2 * scv + shv + x2;
            ov.w = w3 * scv + shv + x3;
        } else {
            ov = *(const float4*)&x[idx];
        }
        *(float4*)&out[idx] = ov;
    }
}

extern "C" void kernel_launch(void* const* d_in, const int* in_sizes, int n_in,
                              void* d_out, int out_size, void* d_ws, size_t ws_size,
                              hipStream_t stream) {
    const float* x     = (const float*)d_in[0];
    const float* spv   = (const float*)d_in[1];
    const float* gw    = (const float*)d_in[2];
    const float* gb    = (const float*)d_in[3];
    const float* pw    = (const float*)d_in[4];
    const float* pb    = (const float*)d_in[5];
    const float* Ww    = (const float*)d_in[6];
    const float* Wb    = (const float*)d_in[7];
    const float* gamma = (const float*)d_in[8];
    const float* beta  = (const float*)d_in[9];
    float* out = (float*)d_out;
    float* ws  = (float*)d_ws;
    const int usew16 = (ws_size >= (size_t)WS_W16_NEED) ? 1 : 0;
    const int use16  = (ws_size >= (size_t)WS_WY_NEED) ? 1 : 0;
    const int usex16 = (ws_size >= (size_t)WS_X16_NEED) ? 1 : 0;
    unsigned short* w16  = (unsigned short*)((char*)d_ws + WS_W16_BYTE);
    unsigned short* wy16 = (unsigned short*)((char*)d_ws + WS_WY_BYTE);
    unsigned short* x16  = (unsigned short*)((char*)d_ws + WS_X16_BYTE);

    k_prep<<<48, 256, 0, stream>>>(gw, pw, Ww, ws, w16, usew16);
    k_pmean<<<1024, 256, 0, stream>>>(x, spv, ws, x16, usex16);
    k_main<<<8192, 256, 0, stream>>>(x, spv, gw, gb, pw, pb, Ww, Wb,
                                     out, wy16, use16, w16, usew16, x16, usex16, ws);
    k_final<<<2048, 256, 0, stream>>>(x, spv, gamma, beta, out, wy16, use16,
                                      x16, usex16, ws);
}

// Round 5
// 130.632 us; speedup vs baseline: 1.0807x; 1.0807x over previous
//
#include <hip/hip_runtime.h>
#include <hip/hip_bf16.h>
#include <math.h>

// Problem constants (b,c,w,h,z) = (2,64,64,64,64), nz = 32
#define THRESH_SP 1.5f
#define WHZc   262144      // 64*64*64
#define CWHZc  16777216    // 64*WHZc

// workspace layout
#define WS_PSUM   0        // [2][64] p sums (floats)
#define WS_SLOT   128      // [32 slots][2][128] {sum,sumsq} interleaved
#define WS_ZERO_N 8320
#define WS_W16_BYTE  65536                    // gw16/pw16/Ww16, 3*4096 u16
#define WS_WY_BYTE   131072                   // wy bf16 [2][CWHZ]
#define WS_W16_NEED  (WS_W16_BYTE + 3u*4096u*2u)
#define WS_WY_NEED   (WS_WY_BYTE + 2u*CWHZc*2u)

typedef __attribute__((ext_vector_type(8))) short bf16x8;
typedef __attribute__((ext_vector_type(4))) float floatx4;

#define MFMA(a, b, c) __builtin_amdgcn_mfma_f32_16x16x32_bf16((a), (b), (c), 0, 0, 0)

__device__ __forceinline__ unsigned short f2b(float f) {
    __hip_bfloat16 h = __float2bfloat16(f);      // native RNE cvt
    return __builtin_bit_cast(unsigned short, h);
}
__device__ __forceinline__ float b2f(unsigned short h) {
    unsigned int u = ((unsigned int)h) << 16;
    return __builtin_bit_cast(float, u);
}
__device__ __forceinline__ bf16x8 ldfrag(const unsigned short* p, int elem_off) {
    return *(const bf16x8*)(p + elem_off);
}

// zero stats + convert the three 64x64 weight matrices to bf16 (once)
__global__ __launch_bounds__(256) void k_prep(const float* __restrict__ gw,
                                              const float* __restrict__ pw,
                                              const float* __restrict__ Ww,
                                              float* __restrict__ ws,
                                              unsigned short* __restrict__ w16,
                                              int usew16) {
    const int i = blockIdx.x * 256 + threadIdx.x;
    if (i < WS_ZERO_N) ws[i] = 0.0f;
    if (usew16 && i < 4096) {
        w16[i]        = f2b(gw[i]);
        w16[4096 + i] = f2b(pw[i]);
        w16[8192 + i] = f2b(Ww[i]);
    }
}

// p[b][z] partial sums
__global__ __launch_bounds__(256) void k_pmean(const float* __restrict__ x,
                                               const float* __restrict__ sp,
                                               float* __restrict__ ws) {
    const int b = blockIdx.x >> 9;
    if (sp[b*3 + 2] > THRESH_SP) return;
    const int jb = blockIdx.x & 511;
    __shared__ float s[64];
    const int t = threadIdx.x;
    if (t < 64) s[t] = 0.0f;
    __syncthreads();
    const int idx4 = jb * 256 + t;
    const int z0 = (idx4 & 15) * 4;
    float a0 = 0.f, a1 = 0.f, a2 = 0.f, a3 = 0.f;
    const float* xb = x + (size_t)b * CWHZc;
#pragma unroll 4
    for (int it = 0; it < 32; ++it) {
        const float4 v = *(const float4*)&xb[(size_t)(idx4 + it * 131072) * 4];
        a0 += v.x; a1 += v.y; a2 += v.z; a3 += v.w;
    }
    a0 += __shfl_xor(a0, 16); a0 += __shfl_xor(a0, 32);
    a1 += __shfl_xor(a1, 16); a1 += __shfl_xor(a1, 32);
    a2 += __shfl_xor(a2, 16); a2 += __shfl_xor(a2, 32);
    a3 += __shfl_xor(a3, 16); a3 += __shfl_xor(a3, 32);
    if ((t & 63) < 16) {
        unsafeAtomicAdd(&s[z0 + 0], a0);
        unsafeAtomicAdd(&s[z0 + 1], a1);
        unsafeAtomicAdd(&s[z0 + 2], a2);
        unsafeAtomicAdd(&s[z0 + 3], a3);
    }
    __syncthreads();
    if (t < 64) unsafeAtomicAdd(&ws[WS_PSUM + b * 64 + t], s[t]);
}

// LDS layout offsets (bytes) for k_main; total 62464 B (static)
#define L_WG     0        // gw [64][72] u16; aliased aT_A after G
#define L_WP     9216     // pw [64][72] u16; Ww staged here during F
#define L_XA     18432    // col A x^T/y^T [64][72] u16
#define L_GPA    27648    // col A gpT [64][40] u16
#define L_PHA    32768    // col A phpN [32][72] u16; aliased f32 stats[128]
#define L_XB     37376
#define L_GPB    46592
#define L_PHB    51712
#define L_ATB    56320    // col B aT [64][40] u16
#define L_BIAS   61440    // f32[192] gb|pb|Wb
#define L_PS     62208    // f32[64] p
#define L_TOTAL  62464

// One block = 2 columns (waves 0-3 col A, 4-7 col B). p factored out of xp.
__global__ __launch_bounds__(512, 4) void k_main(
    const float* __restrict__ x, const float* __restrict__ sp,
    const float* __restrict__ gw, const float* __restrict__ gb,
    const float* __restrict__ pw, const float* __restrict__ pb,
    const float* __restrict__ Wwp, const float* __restrict__ Wbp,
    float* __restrict__ out, unsigned short* __restrict__ wy16, int use16,
    const unsigned short* __restrict__ w16, int usew16,
    float* __restrict__ ws) {
    const int blk = blockIdx.x;
    const int b = blk >> 11;
    if (sp[b*3 + 2] > THRESH_SP) return;
    const int whpair = (blk & 2047) * 2;

    __shared__ char smem[L_TOTAL];
    unsigned short* wg   = (unsigned short*)(smem + L_WG);
    unsigned short* wp   = (unsigned short*)(smem + L_WP);
    float*          bias = (float*)(smem + L_BIAS);
    float*          p_s  = (float*)(smem + L_PS);
    float*          statsf = (float*)(smem + L_PHA);

    const int t   = threadIdx.x;
    const int wv  = t >> 6;          // wave 0..7
    const int cid = wv >> 2;         // column 0/1
    const int tt  = t & 255;         // id within column group
    const int l   = t & 63;
    const int lr  = l & 15;
    const int lq  = l >> 4;
    const int zt  = (wv & 3) << 4;   // z band within column

    unsigned short* xT   = (unsigned short*)(smem + (cid ? L_XB  : L_XA));
    unsigned short* gpT  = (unsigned short*)(smem + (cid ? L_GPB : L_GPA));
    unsigned short* phpN = (unsigned short*)(smem + (cid ? L_PHB : L_PHA));
    unsigned short* aT   = (unsigned short*)(smem + (cid ? L_ATB : L_WG));

    const int wh    = whpair + cid;
    const int xbase = b * CWHZc + wh * 64;

    // ---- P0: stage x^T (own column), gw+pw, biases, p ----
#pragma unroll
    for (int k = 0; k < 4; ++k) {
        const int f = tt + (k << 8);
        const int c = f & 63, zq = f >> 6;
        const float4 v = *(const float4*)&x[xbase + c * WHZc + zq * 4];
        xT[(zq*4 + 0)*72 + c] = f2b(v.x);
        xT[(zq*4 + 1)*72 + c] = f2b(v.y);
        xT[(zq*4 + 2)*72 + c] = f2b(v.z);
        xT[(zq*4 + 3)*72 + c] = f2b(v.w);
    }
    if (usew16) {
#pragma unroll
        for (int k = 0; k < 2; ++k) {
            const int f = t + (k << 9);              // 0..1023 uint4 slots
            const int mat = f >> 9;
            const int i = (f & 511) >> 3, seg = f & 7;
            unsigned short* dst = mat ? wp : wg;
            *(uint4*)&dst[i*72 + seg*8] = *(const uint4*)&w16[mat*4096 + i*64 + seg*8];
        }
    } else {
#pragma unroll
        for (int k = 0; k < 4; ++k) {
            const int f = t + (k << 9);              // 0..2047 float4 slots
            const int mat = f >> 10, ff = f & 1023;
            const int i = ff >> 4, c4 = ff & 15;
            const float* src = mat ? pw : gw;
            unsigned short* dst = mat ? wp : wg;
            const float4 v = *(const float4*)&src[i*64 + c4*4];
            uint2 pk;
            pk.x = (unsigned)f2b(v.x) | ((unsigned)f2b(v.y) << 16);
            pk.y = (unsigned)f2b(v.z) | ((unsigned)f2b(v.w) << 16);
            *(uint2*)&dst[i*72 + c4*4] = pk;
        }
    }
    if (t < 192) bias[t] = (t < 64) ? gb[t] : (t < 128) ? pb[t - 64] : Wbp[t - 128];
    if (t < 64)  p_s[t] = ws[WS_PSUM + b*64 + t] * (1.0f / 262144.0f);
    __syncthreads();

    // persistent A-fragments of x^T (rows z = zt+lr, k = c)
    const bf16x8 a0 = ldfrag(xT, (zt + lr)*72 + lq*8);
    const bf16x8 a1 = ldfrag(xT, (zt + lr)*72 + lq*8 + 32);
    const float pz0 = p_s[zt + lq*4 + 0], pz1 = p_s[zt + lq*4 + 1];
    const float pz2 = p_s[zt + lq*4 + 2], pz3 = p_s[zt + lq*4 + 3];

    // ---- P1 G: D[z][i] = sum_c x[z][c]*gw[i][c] + gb; maxpool -> gpT[i][n] ----
    {
        const int n0 = (zt >> 1) + lq*2;
#pragma unroll
        for (int ti = 0; ti < 4; ++ti) {
            const int i = ti*16 + lr;
            const float bv = bias[i];
            floatx4 acc = {bv, bv, bv, bv};
            acc = MFMA(a0, ldfrag(wg, i*72 + lq*8), acc);
            acc = MFMA(a1, ldfrag(wg, i*72 + lq*8 + 32), acc);
            unsigned int pk = (unsigned)f2b(fmaxf(acc[0], acc[1])) |
                              ((unsigned)f2b(fmaxf(acc[2], acc[3])) << 16);
            *(unsigned int*)&gpT[i*40 + n0] = pk;
        }
    }
    __syncthreads();

    // ---- P2 PHI: phi[z][i] = p[z]*(X Wp^T)[z][i] + pb; pool -> phpN[n][i] ----
    {
        const int n0 = (zt >> 1) + lq*2;
#pragma unroll
        for (int ti = 0; ti < 4; ++ti) {
            const int i = ti*16 + lr;
            floatx4 acc = {0.f, 0.f, 0.f, 0.f};
            acc = MFMA(a0, ldfrag(wp, i*72 + lq*8), acc);
            acc = MFMA(a1, ldfrag(wp, i*72 + lq*8 + 32), acc);
            const float bv = bias[64 + i];
            const float v0 = fmaf(acc[0], pz0, bv), v1 = fmaf(acc[1], pz1, bv);
            const float v2 = fmaf(acc[2], pz2, bv), v3 = fmaf(acc[3], pz3, bv);
            phpN[n0*72 + i]       = f2b(fmaxf(v0, v1));
            phpN[(n0 + 1)*72 + i] = f2b(fmaxf(v2, v3));
        }
    }
    __syncthreads();

    // ---- P3 F + softmax -> aT; stage Ww into wp ----
    {
        floatx4 f0 = {0.f, 0.f, 0.f, 0.f}, f1 = {0.f, 0.f, 0.f, 0.f};
        f0 = MFMA(a0, ldfrag(phpN, lr*72 + lq*8), f0);
        f0 = MFMA(a1, ldfrag(phpN, lr*72 + lq*8 + 32), f0);
        f1 = MFMA(a0, ldfrag(phpN, (16 + lr)*72 + lq*8), f1);
        f1 = MFMA(a1, ldfrag(phpN, (16 + lr)*72 + lq*8 + 32), f1);
        if (usew16) {
            const int i = t >> 3, seg = t & 7;       // 512 slots covers 4096
            *(uint4*)&wp[i*72 + seg*8] = *(const uint4*)&w16[8192 + i*64 + seg*8];
        } else {
#pragma unroll
            for (int k = 0; k < 2; ++k) {
                const int f = t + (k << 9);
                const int i = f >> 4, c4 = f & 15;
                const float4 v = *(const float4*)&Wwp[i*64 + c4*4];
                uint2 pk;
                pk.x = (unsigned)f2b(v.x) | ((unsigned)f2b(v.y) << 16);
                pk.y = (unsigned)f2b(v.z) | ((unsigned)f2b(v.w) << 16);
                *(uint2*)&wp[i*72 + c4*4] = pk;
            }
        }
        const float pz[4] = {pz0, pz1, pz2, pz3};
#pragma unroll
        for (int r = 0; r < 4; ++r) {
            const float fr0 = f0[r] * pz[r], fr1 = f1[r] * pz[r];
            float m = fmaxf(fr0, fr1);
            m = fmaxf(m, __shfl_xor(m, 1)); m = fmaxf(m, __shfl_xor(m, 2));
            m = fmaxf(m, __shfl_xor(m, 4)); m = fmaxf(m, __shfl_xor(m, 8));
            const float e0 = __expf(fr0 - m), e1 = __expf(fr1 - m);
            float s = e0 + e1;
            s += __shfl_xor(s, 1); s += __shfl_xor(s, 2);
            s += __shfl_xor(s, 4); s += __shfl_xor(s, 8);
            const float inv = 1.0f / s;
            const int z = zt + lq*4 + r;
            aT[z*40 + lr]      = f2b(e0 * inv);
            aT[z*40 + lr + 16] = f2b(e1 * inv);
        }
    }
    __syncthreads();

    // ---- P4 Y: y[z][i] = sum_n a[z][n]*gp[i][n] -> y^T into xT; zero stats ----
    {
        if (t < 128) statsf[t] = 0.0f;
        const bf16x8 av = ldfrag(aT, (zt + lr)*40 + lq*8);
#pragma unroll
        for (int ti = 0; ti < 4; ++ti) {
            floatx4 acc = {0.f, 0.f, 0.f, 0.f};
            acc = MFMA(av, ldfrag(gpT, (ti*16 + lr)*40 + lq*8), acc);
#pragma unroll
            for (int r = 0; r < 4; ++r)
                xT[(zt + lq*4 + r)*72 + ti*16 + lr] = f2b(acc[r]);
        }
    }
    __syncthreads();

    // ---- P5 W: wy^T[z][co] = sum_i y[z][i]*Ww[co][i] + Wb; store + BN stats ----
    {
        const bf16x8 y0 = ldfrag(xT, (zt + lr)*72 + lq*8);
        const bf16x8 y1 = ldfrag(xT, (zt + lr)*72 + lq*8 + 32);
#pragma unroll
        for (int ti = 0; ti < 4; ++ti) {
            const int co = ti*16 + lr;
            const float bv = bias[128 + co];
            floatx4 acc = {bv, bv, bv, bv};
            acc = MFMA(y0, ldfrag(wp, co*72 + lq*8), acc);
            acc = MFMA(y1, ldfrag(wp, co*72 + lq*8 + 32), acc);
            if (use16) {
                uint2 pk;
                pk.x = (unsigned)f2b(acc[0]) | ((unsigned)f2b(acc[1]) << 16);
                pk.y = (unsigned)f2b(acc[2]) | ((unsigned)f2b(acc[3]) << 16);
                *(uint2*)&wy16[(size_t)xbase + co * WHZc + zt + lq*4] = pk;
            } else {
                *(float4*)&out[xbase + co * WHZc + zt + lq*4] = *(float4*)&acc;
            }
            float s1 = acc[0] + acc[1] + acc[2] + acc[3];
            float s2 = acc[0]*acc[0] + acc[1]*acc[1] + acc[2]*acc[2] + acc[3]*acc[3];
            s1 += __shfl_xor(s1, 16); s1 += __shfl_xor(s1, 32);
            s2 += __shfl_xor(s2, 16); s2 += __shfl_xor(s2, 32);
            if (lq == 0) {
                atomicAdd(&statsf[co*2],     s1);
                atomicAdd(&statsf[co*2 + 1], s2);
            }
        }
    }
    __syncthreads();
    if (t < 128) {
        const int slot = blk & 31;
        unsafeAtomicAdd(&ws[WS_SLOT + (slot*2 + b)*128 + t], statsf[t]);
    }
}

// out = gate ? wy*sc + sh + x : x  (BN finalize folded in)
__global__ __launch_bounds__(256) void k_final(const float* __restrict__ x,
                                               const float* __restrict__ sp,
                                               const float* __restrict__ gamma,
                                               const float* __restrict__ beta,
                                               float* __restrict__ out,
                                               const unsigned short* __restrict__ wy16,
                                               int use16,
                                               const float* __restrict__ ws) {
    const bool use0 = sp[2] <= THRESH_SP;
    const bool use1 = sp[5] <= THRESH_SP;
    __shared__ float scf[128], shf[128];
    if ((use0 || use1) && threadIdx.x < 128) {
        const int t = threadIdx.x;
        const int b = t >> 6, c = t & 63;
        float S1 = 0.f, S2 = 0.f;
        for (int s = 0; s < 32; s++) {
            S1 += ws[WS_SLOT + (s*2 + b)*128 + c*2 + 0];
            S2 += ws[WS_SLOT + (s*2 + b)*128 + c*2 + 1];
        }
        const float N = 262144.0f;
        const float mu = S1 / N;
        const float var = fmaxf(S2 / N - mu * mu, 0.0f);
        const float sc = gamma[c] * rsqrtf(var + 1e-5f);
        scf[t] = sc;
        shf[t] = beta[c] - mu * sc;
    }
    __syncthreads();
    const int nf4 = (2 * CWHZc) / 4;
    for (int i4 = blockIdx.x * blockDim.x + threadIdx.x; i4 < nf4;
         i4 += gridDim.x * blockDim.x) {
        const int idx = i4 * 4;
        const int b = idx >> 24;
        const bool use = b ? use1 : use0;
        const float4 xv = *(const float4*)&x[idx];
        float4 ov;
        if (use) {
            const int c = (idx >> 18) & 63;
            const float scv = scf[b * 64 + c];
            const float shv = shf[b * 64 + c];
            float w0, w1, w2, w3;
            if (use16) {
                const uint2 q = *(const uint2*)&wy16[idx];
                w0 = b2f((unsigned short)(q.x & 0xffffu));
                w1 = b2f((unsigned short)(q.x >> 16));
                w2 = b2f((unsigned short)(q.y & 0xffffu));
                w3 = b2f((unsigned short)(q.y >> 16));
            } else {
                const float4 wy = *(const float4*)&out[idx];
                w0 = wy.x; w1 = wy.y; w2 = wy.z; w3 = wy.w;
            }
            ov.x = w0 * scv + shv + xv.x;
            ov.y = w1 * scv + shv + xv.y;
            ov.z = w2 * scv + shv + xv.z;
            ov.w = w3 * scv + shv + xv.w;
        } else {
            ov = xv;
        }
        *(float4*)&out[idx] = ov;
    }
}

extern "C" void kernel_launch(void* const* d_in, const int* in_sizes, int n_in,
                              void* d_out, int out_size, void* d_ws, size_t ws_size,
                              hipStream_t stream) {
    const float* x     = (const float*)d_in[0];
    const float* spv   = (const float*)d_in[1];
    const float* gw    = (const float*)d_in[2];
    const float* gb    = (const float*)d_in[3];
    const float* pw    = (const float*)d_in[4];
    const float* pb    = (const float*)d_in[5];
    const float* Ww    = (const float*)d_in[6];
    const float* Wb    = (const float*)d_in[7];
    const float* gamma = (const float*)d_in[8];
    const float* beta  = (const float*)d_in[9];
    float* out = (float*)d_out;
    float* ws  = (float*)d_ws;
    const int usew16 = (ws_size >= (size_t)WS_W16_NEED) ? 1 : 0;
    const int use16  = (ws_size >= (size_t)WS_WY_NEED) ? 1 : 0;
    unsigned short* w16  = (unsigned short*)((char*)d_ws + WS_W16_BYTE);
    unsigned short* wy16 = (unsigned short*)((char*)d_ws + WS_WY_BYTE);

    k_prep<<<48, 256, 0, stream>>>(gw, pw, Ww, ws, w16, usew16);
    k_pmean<<<1024, 256, 0, stream>>>(x, spv, ws);
    k_main<<<4096, 512, 0, stream>>>(x, spv, gw, gb, pw, pb, Ww, Wb,
                                     out, wy16, use16, w16, usew16, ws);
    k_final<<<2048, 256, 0, stream>>>(x, spv, gamma, beta, out, wy16, use16, ws);
}

// Round 7
// 128.369 us; speedup vs baseline: 1.0998x; 1.0176x over previous
//
#include <hip/hip_runtime.h>
#include <hip/hip_bf16.h>
#include <math.h>

// Problem constants (b,c,w,h,z) = (2,64,64,64,64), nz = 32
#define THRESH_SP 1.5f
#define WHZc   262144      // 64*64*64
#define CWHZc  16777216    // 64*WHZc

// workspace layout
#define WS_PSUM   0        // [2][64] p sums (floats)
#define WS_SLOT   128      // [32 slots][2][128] {sum,sumsq} interleaved
#define WS_ZERO_N 8320
#define WS_W16_BYTE  65536                    // gw16/pw16/Ww16, 3*4096 u16
#define WS_WY_BYTE   131072                   // wy bf16 [2][CWHZ]
#define WS_W16_NEED  (WS_W16_BYTE + 3u*4096u*2u)
#define WS_WY_NEED   (WS_WY_BYTE + 2u*CWHZc*2u)

typedef __attribute__((ext_vector_type(8))) short bf16x8;
typedef __attribute__((ext_vector_type(4))) float floatx4;
typedef __attribute__((ext_vector_type(4))) float f32x4;
typedef __attribute__((ext_vector_type(2))) unsigned int u32x2;

#define MFMA(a, b, c) __builtin_amdgcn_mfma_f32_16x16x32_bf16((a), (b), (c), 0, 0, 0)

__device__ __forceinline__ unsigned short f2b(float f) {
    __hip_bfloat16 h = __float2bfloat16(f);      // native RNE cvt
    return __builtin_bit_cast(unsigned short, h);
}
__device__ __forceinline__ float b2f(unsigned short h) {
    unsigned int u = ((unsigned int)h) << 16;
    return __builtin_bit_cast(float, u);
}
__device__ __forceinline__ bf16x8 ldfrag(const unsigned short* p, int elem_off) {
    return *(const bf16x8*)(p + elem_off);
}

// zero stats + convert the three 64x64 weight matrices to bf16 (once)
__global__ __launch_bounds__(256) void k_prep(const float* __restrict__ gw,
                                              const float* __restrict__ pw,
                                              const float* __restrict__ Ww,
                                              float* __restrict__ ws,
                                              unsigned short* __restrict__ w16,
                                              int usew16) {
    const int i = blockIdx.x * 256 + threadIdx.x;
    if (i < WS_ZERO_N) ws[i] = 0.0f;
    if (usew16 && i < 4096) {
        w16[i]        = f2b(gw[i]);
        w16[4096 + i] = f2b(pw[i]);
        w16[8192 + i] = f2b(Ww[i]);
    }
}

// p[b][z] partial sums
__global__ __launch_bounds__(256) void k_pmean(const float* __restrict__ x,
                                               const float* __restrict__ sp,
                                               float* __restrict__ ws) {
    const int b = blockIdx.x >> 9;
    if (sp[b*3 + 2] > THRESH_SP) return;
    const int jb = blockIdx.x & 511;
    __shared__ float s[64];
    const int t = threadIdx.x;
    if (t < 64) s[t] = 0.0f;
    __syncthreads();
    const int idx4 = jb * 256 + t;
    const int z0 = (idx4 & 15) * 4;
    float a0 = 0.f, a1 = 0.f, a2 = 0.f, a3 = 0.f;
    const float* xb = x + (size_t)b * CWHZc;
#pragma unroll 4
    for (int it = 0; it < 32; ++it) {
        const float4 v = *(const float4*)&xb[(size_t)(idx4 + it * 131072) * 4];
        a0 += v.x; a1 += v.y; a2 += v.z; a3 += v.w;
    }
    a0 += __shfl_xor(a0, 16); a0 += __shfl_xor(a0, 32);
    a1 += __shfl_xor(a1, 16); a1 += __shfl_xor(a1, 32);
    a2 += __shfl_xor(a2, 16); a2 += __shfl_xor(a2, 32);
    a3 += __shfl_xor(a3, 16); a3 += __shfl_xor(a3, 32);
    if ((t & 63) < 16) {
        unsafeAtomicAdd(&s[z0 + 0], a0);
        unsafeAtomicAdd(&s[z0 + 1], a1);
        unsafeAtomicAdd(&s[z0 + 2], a2);
        unsafeAtomicAdd(&s[z0 + 3], a3);
    }
    __syncthreads();
    if (t < 64) unsafeAtomicAdd(&ws[WS_PSUM + b * 64 + t], s[t]);
}

// LDS layout offsets (bytes) for k_main; total 62464 B (static)
#define L_WG     0        // gw [64][72] u16; aliased aT_A after G
#define L_WP     9216     // pw [64][72] u16; Ww staged here during F
#define L_XA     18432    // col A x^T/y^T [64][72] u16 (XOR-chunk swizzled)
#define L_GPA    27648    // col A gpT [64][40] u16
#define L_PHA    32768    // col A phpN [32][72] u16; aliased f32 stats[128]
#define L_XB     37376
#define L_GPB    46592
#define L_PHB    51712
#define L_ATB    56320    // col B aT [64][40] u16
#define L_BIAS   61440    // f32[192] gb|pb|Wb
#define L_PS     62208    // f32[64] p
#define L_TOTAL  62464

// One block = 2 columns (waves 0-3 col A, 4-7 col B). p factored out of xp.
// xT uses chunk-XOR swizzle: elem(z,c) = z*72 + ((c>>3)^((z>>2)&3))*8 + (c&7)
__global__ __launch_bounds__(512, 4) void k_main(
    const float* __restrict__ x, const float* __restrict__ sp,
    const float* __restrict__ gw, const float* __restrict__ gb,
    const float* __restrict__ pw, const float* __restrict__ pb,
    const float* __restrict__ Wwp, const float* __restrict__ Wbp,
    float* __restrict__ out, unsigned short* __restrict__ wy16, int use16,
    const unsigned short* __restrict__ w16, int usew16,
    float* __restrict__ ws) {
    const int blk = blockIdx.x;
    const int b = blk >> 11;
    if (sp[b*3 + 2] > THRESH_SP) return;
    const int whpair = (blk & 2047) * 2;

    __shared__ char smem[L_TOTAL];
    unsigned short* wg   = (unsigned short*)(smem + L_WG);
    unsigned short* wp   = (unsigned short*)(smem + L_WP);
    float*          bias = (float*)(smem + L_BIAS);
    float*          p_s  = (float*)(smem + L_PS);
    float*          statsf = (float*)(smem + L_PHA);

    const int t   = threadIdx.x;
    const int wv  = t >> 6;          // wave 0..7
    const int cid = wv >> 2;         // column 0/1
    const int tt  = t & 255;         // id within column group
    const int l   = t & 63;
    const int lr  = l & 15;
    const int lq  = l >> 4;
    const int zt  = (wv & 3) << 4;   // z band within column

    unsigned short* xT   = (unsigned short*)(smem + (cid ? L_XB  : L_XA));
    unsigned short* gpT  = (unsigned short*)(smem + (cid ? L_GPB : L_GPA));
    unsigned short* phpN = (unsigned short*)(smem + (cid ? L_PHB : L_PHA));
    unsigned short* aT   = (unsigned short*)(smem + (cid ? L_ATB : L_WG));

    const int wh    = whpair + cid;
    const int xbase = b * CWHZc + wh * 64;

    // ---- P0: stage x^T coalesced (z-fastest lanes, packed b32 pair writes) ----
    {
        const int pr = tt >> 3;          // c-pair 0..31
        const int zo = tt & 7;           // z-quad 0..7 (+8)
        const int c0 = pr * 2;
        const float* xc = &x[xbase + c0 * WHZc];
        const float4 A0 = *(const float4*)&xc[zo * 4];
        const float4 A1 = *(const float4*)&xc[zo * 4 + 32];
        const float4 B0 = *(const float4*)&xc[WHZc + zo * 4];
        const float4 B1 = *(const float4*)&xc[WHZc + zo * 4 + 32];
#pragma unroll
        for (int g = 0; g < 2; ++g) {
            const float4 va = g ? A1 : A0;
            const float4 vb = g ? B1 : B0;
            const int zb = (zo + 8 * g) * 4;
            const float av[4] = {va.x, va.y, va.z, va.w};
            const float bw[4] = {vb.x, vb.y, vb.z, vb.w};
#pragma unroll
            for (int j = 0; j < 4; ++j) {
                const int z = zb + j;
                const int chunk = (c0 >> 3) ^ ((z >> 2) & 3);
                const unsigned int pk =
                    (unsigned)f2b(av[j]) | ((unsigned)f2b(bw[j]) << 16);
                *(unsigned int*)&xT[z * 72 + chunk * 8 + (c0 & 7)] = pk;
            }
        }
    }
    if (usew16) {
#pragma unroll
        for (int k = 0; k < 2; ++k) {
            const int f = t + (k << 9);              // 0..1023 uint4 slots
            const int mat = f >> 9;
            const int i = (f & 511) >> 3, seg = f & 7;
            unsigned short* dst = mat ? wp : wg;
            *(uint4*)&dst[i*72 + seg*8] = *(const uint4*)&w16[mat*4096 + i*64 + seg*8];
        }
    } else {
#pragma unroll
        for (int k = 0; k < 4; ++k) {
            const int f = t + (k << 9);              // 0..2047 float4 slots
            const int mat = f >> 10, ff = f & 1023;
            const int i = ff >> 4, c4 = ff & 15;
            const float* src = mat ? pw : gw;
            unsigned short* dst = mat ? wp : wg;
            const float4 v = *(const float4*)&src[i*64 + c4*4];
            uint2 pk;
            pk.x = (unsigned)f2b(v.x) | ((unsigned)f2b(v.y) << 16);
            pk.y = (unsigned)f2b(v.z) | ((unsigned)f2b(v.w) << 16);
            *(uint2*)&dst[i*72 + c4*4] = pk;
        }
    }
    if (t < 192) bias[t] = (t < 64) ? gb[t] : (t < 128) ? pb[t - 64] : Wbp[t - 128];
    if (t < 64)  p_s[t] = ws[WS_PSUM + b*64 + t] * (1.0f / 262144.0f);
    __syncthreads();

    // persistent A-fragments of x^T (rows z = zt+lr, k = c) via XOR'd chunks
    const int zrow  = zt + lr;
    const int abase = zrow * 72 + ((lq ^ ((zrow >> 2) & 3)) << 3);
    const bf16x8 a0 = ldfrag(xT, abase);
    const bf16x8 a1 = ldfrag(xT, abase + 32);
    const float pz0 = p_s[zt + lq*4 + 0], pz1 = p_s[zt + lq*4 + 1];
    const float pz2 = p_s[zt + lq*4 + 2], pz3 = p_s[zt + lq*4 + 3];

    // ---- P1 G: D[z][i] = sum_c x[z][c]*gw[i][c] + gb; maxpool -> gpT[i][n] ----
    {
        const int n0 = (zt >> 1) + lq*2;
#pragma unroll
        for (int ti = 0; ti < 4; ++ti) {
            const int i = ti*16 + lr;
            const float bv = bias[i];
            floatx4 acc = {bv, bv, bv, bv};
            acc = MFMA(a0, ldfrag(wg, i*72 + lq*8), acc);
            acc = MFMA(a1, ldfrag(wg, i*72 + lq*8 + 32), acc);
            unsigned int pk = (unsigned)f2b(fmaxf(acc[0], acc[1])) |
                              ((unsigned)f2b(fmaxf(acc[2], acc[3])) << 16);
            *(unsigned int*)&gpT[i*40 + n0] = pk;
        }
    }
    __syncthreads();

    // ---- P2 PHI: phi[z][i] = p[z]*(X Wp^T)[z][i] + pb; pool -> phpN[n][i] ----
    {
        const int n0 = (zt >> 1) + lq*2;
#pragma unroll
        for (int ti = 0; ti < 4; ++ti) {
            const int i = ti*16 + lr;
            floatx4 acc = {0.f, 0.f, 0.f, 0.f};
            acc = MFMA(a0, ldfrag(wp, i*72 + lq*8), acc);
            acc = MFMA(a1, ldfrag(wp, i*72 + lq*8 + 32), acc);
            const float bv = bias[64 + i];
            const float v0 = fmaf(acc[0], pz0, bv), v1 = fmaf(acc[1], pz1, bv);
            const float v2 = fmaf(acc[2], pz2, bv), v3 = fmaf(acc[3], pz3, bv);
            phpN[n0*72 + i]       = f2b(fmaxf(v0, v1));
            phpN[(n0 + 1)*72 + i] = f2b(fmaxf(v2, v3));
        }
    }
    __syncthreads();

    // ---- P3 F + softmax -> aT; stage Ww into wp ----
    {
        floatx4 f0 = {0.f, 0.f, 0.f, 0.f}, f1 = {0.f, 0.f, 0.f, 0.f};
        f0 = MFMA(a0, ldfrag(phpN, lr*72 + lq*8), f0);
        f0 = MFMA(a1, ldfrag(phpN, lr*72 + lq*8 + 32), f0);
        f1 = MFMA(a0, ldfrag(phpN, (16 + lr)*72 + lq*8), f1);
        f1 = MFMA(a1, ldfrag(phpN, (16 + lr)*72 + lq*8 + 32), f1);
        if (usew16) {
            const int i = t >> 3, seg = t & 7;       // 512 slots covers 4096
            *(uint4*)&wp[i*72 + seg*8] = *(const uint4*)&w16[8192 + i*64 + seg*8];
        } else {
#pragma unroll
            for (int k = 0; k < 2; ++k) {
                const int f = t + (k << 9);
                const int i = f >> 4, c4 = f & 15;
                const float4 v = *(const float4*)&Wwp[i*64 + c4*4];
                uint2 pk;
                pk.x = (unsigned)f2b(v.x) | ((unsigned)f2b(v.y) << 16);
                pk.y = (unsigned)f2b(v.z) | ((unsigned)f2b(v.w) << 16);
                *(uint2*)&wp[i*72 + c4*4] = pk;
            }
        }
        const float pz[4] = {pz0, pz1, pz2, pz3};
#pragma unroll
        for (int r = 0; r < 4; ++r) {
            const float fr0 = f0[r] * pz[r], fr1 = f1[r] * pz[r];
            float m = fmaxf(fr0, fr1);
            m = fmaxf(m, __shfl_xor(m, 1)); m = fmaxf(m, __shfl_xor(m, 2));
            m = fmaxf(m, __shfl_xor(m, 4)); m = fmaxf(m, __shfl_xor(m, 8));
            const float e0 = __expf(fr0 - m), e1 = __expf(fr1 - m);
            float s = e0 + e1;
            s += __shfl_xor(s, 1); s += __shfl_xor(s, 2);
            s += __shfl_xor(s, 4); s += __shfl_xor(s, 8);
            const float inv = 1.0f / s;
            const int z = zt + lq*4 + r;
            aT[z*40 + lr]      = f2b(e0 * inv);
            aT[z*40 + lr + 16] = f2b(e1 * inv);
        }
    }
    __syncthreads();

    // ---- P4 Y as D[i][z]: A=gpT[i][n], B=aT[z][n]; lane holds 4 consec i at one z
    //      -> packed b64 y^T writes into xT (XOR chunks); zero stats ----
    {
        if (t < 128) statsf[t] = 0.0f;
        const bf16x8 bv = ldfrag(aT, (zt + lr)*40 + lq*8);
        const int zcol = zt + lr;
        const int xzc = (zcol >> 2) & 3;
#pragma unroll
        for (int it = 0; it < 4; ++it) {
            const bf16x8 av = ldfrag(gpT, (it*16 + lr)*40 + lq*8);
            floatx4 acc = {0.f, 0.f, 0.f, 0.f};
            acc = MFMA(av, bv, acc);
            const int i0 = it*16 + lq*4;
            const int chunk = (i0 >> 3) ^ xzc;
            uint2 pk;
            pk.x = (unsigned)f2b(acc[0]) | ((unsigned)f2b(acc[1]) << 16);
            pk.y = (unsigned)f2b(acc[2]) | ((unsigned)f2b(acc[3]) << 16);
            *(uint2*)&xT[zcol*72 + chunk*8 + (i0 & 7)] = pk;
        }
    }
    __syncthreads();

    // ---- P5 W: wy^T[z][co] = sum_i y[z][i]*Ww[co][i] + Wb; store + BN stats ----
    {
        const bf16x8 y0 = ldfrag(xT, abase);          // same XOR'd base as a0/a1
        const bf16x8 y1 = ldfrag(xT, abase + 32);
#pragma unroll
        for (int ti = 0; ti < 4; ++ti) {
            const int co = ti*16 + lr;
            const float bv = bias[128 + co];
            floatx4 acc = {bv, bv, bv, bv};
            acc = MFMA(y0, ldfrag(wp, co*72 + lq*8), acc);
            acc = MFMA(y1, ldfrag(wp, co*72 + lq*8 + 32), acc);
            if (use16) {
                uint2 pk;
                pk.x = (unsigned)f2b(acc[0]) | ((unsigned)f2b(acc[1]) << 16);
                pk.y = (unsigned)f2b(acc[2]) | ((unsigned)f2b(acc[3]) << 16);
                *(uint2*)&wy16[(size_t)xbase + co * WHZc + zt + lq*4] = pk;
            } else {
                *(float4*)&out[xbase + co * WHZc + zt + lq*4] = *(float4*)&acc;
            }
            float s1 = acc[0] + acc[1] + acc[2] + acc[3];
            float s2 = acc[0]*acc[0] + acc[1]*acc[1] + acc[2]*acc[2] + acc[3]*acc[3];
            s1 += __shfl_xor(s1, 16); s1 += __shfl_xor(s1, 32);
            s2 += __shfl_xor(s2, 16); s2 += __shfl_xor(s2, 32);
            if (lq == 0) {
                atomicAdd(&statsf[co*2],     s1);
                atomicAdd(&statsf[co*2 + 1], s2);
            }
        }
    }
    __syncthreads();
    if (t < 128) {
        const int slot = blk & 31;
        unsafeAtomicAdd(&ws[WS_SLOT + (slot*2 + b)*128 + t], statsf[t]);
    }
}

// out = gate ? wy*sc + sh + x : x  (BN finalize folded in; non-temporal streams)
__global__ __launch_bounds__(256) void k_final(const float* __restrict__ x,
                                               const float* __restrict__ sp,
                                               const float* __restrict__ gamma,
                                               const float* __restrict__ beta,
                                               float* __restrict__ out,
                                               const unsigned short* __restrict__ wy16,
                                               int use16,
                                               const float* __restrict__ ws) {
    const bool use0 = sp[2] <= THRESH_SP;
    const bool use1 = sp[5] <= THRESH_SP;
    __shared__ float scf[128], shf[128];
    if ((use0 || use1) && threadIdx.x < 128) {
        const int t = threadIdx.x;
        const int b = t >> 6, c = t & 63;
        float S1 = 0.f, S2 = 0.f;
        for (int s = 0; s < 32; s++) {
            S1 += ws[WS_SLOT + (s*2 + b)*128 + c*2 + 0];
            S2 += ws[WS_SLOT + (s*2 + b)*128 + c*2 + 1];
        }
        const float N = 262144.0f;
        const float mu = S1 / N;
        const float var = fmaxf(S2 / N - mu * mu, 0.0f);
        const float sc = gamma[c] * rsqrtf(var + 1e-5f);
        scf[t] = sc;
        shf[t] = beta[c] - mu * sc;
    }
    __syncthreads();
    const int nf4 = (2 * CWHZc) / 4;
    for (int i4 = blockIdx.x * blockDim.x + threadIdx.x; i4 < nf4;
         i4 += gridDim.x * blockDim.x) {
        const int idx = i4 * 4;
        const int b = idx >> 24;
        const bool use = b ? use1 : use0;
        const f32x4 xv = __builtin_nontemporal_load((const f32x4*)&x[idx]);
        f32x4 ov;
        if (use) {
            const int c = (idx >> 18) & 63;
            const float scv = scf[b * 64 + c];
            const float shv = shf[b * 64 + c];
            float w0, w1, w2, w3;
            if (use16) {
                const u32x2 q = __builtin_nontemporal_load((const u32x2*)&wy16[idx]);
                w0 = b2f((unsigned short)(q.x & 0xffffu));
                w1 = b2f((unsigned short)(q.x >> 16));
                w2 = b2f((unsigned short)(q.y & 0xffffu));
                w3 = b2f((unsigned short)(q.y >> 16));
            } else {
                const float4 wy = *(const float4*)&out[idx];
                w0 = wy.x; w1 = wy.y; w2 = wy.z; w3 = wy.w;
            }
            ov.x = w0 * scv + shv + xv.x;
            ov.y = w1 * scv + shv + xv.y;
            ov.z = w2 * scv + shv + xv.z;
            ov.w = w3 * scv + shv + xv.w;
        } else {
            ov = xv;
        }
        __builtin_nontemporal_store(ov, (f32x4*)&out[idx]);
    }
}

extern "C" void kernel_launch(void* const* d_in, const int* in_sizes, int n_in,
                              void* d_out, int out_size, void* d_ws, size_t ws_size,
                              hipStream_t stream) {
    const float* x     = (const float*)d_in[0];
    const float* spv   = (const float*)d_in[1];
    const float* gw    = (const float*)d_in[2];
    const float* gb    = (const float*)d_in[3];
    const float* pw    = (const float*)d_in[4];
    const float* pb    = (const float*)d_in[5];
    const float* Ww    = (const float*)d_in[6];
    const float* Wb    = (const float*)d_in[7];
    const float* gamma = (const float*)d_in[8];
    const float* beta  = (const float*)d_in[9];
    float* out = (float*)d_out;
    float* ws  = (float*)d_ws;
    const int usew16 = (ws_size >= (size_t)WS_W16_NEED) ? 1 : 0;
    const int use16  = (ws_size >= (size_t)WS_WY_NEED) ? 1 : 0;
    unsigned short* w16  = (unsigned short*)((char*)d_ws + WS_W16_BYTE);
    unsigned short* wy16 = (unsigned short*)((char*)d_ws + WS_WY_BYTE);

    k_prep<<<48, 256, 0, stream>>>(gw, pw, Ww, ws, w16, usew16);
    k_pmean<<<1024, 256, 0, stream>>>(x, spv, ws);
    k_main<<<4096, 512, 0, stream>>>(x, spv, gw, gb, pw, pb, Ww, Wb,
                                     out, wy16, use16, w16, usew16, ws);
    k_final<<<2048, 256, 0, stream>>>(x, spv, gamma, beta, out, wy16, use16, ws);
}